// Round 3
// 107.904 us; speedup vs baseline: 1.0049x; 1.0049x over previous
//
#include <hip/hip_runtime.h>
#include <hip/hip_bf16.h>

// out[b] = 0.1*log1p(1/S_b),  S_b = sum_k exp2(z*H(z) + log2(w_k)), z=(1-ip)/2
// R6: bisect outcome — R4/R5 shared-code failure convicts the raw VOP3P
// inline asm (op_sel default suspect). Same packed-pair epilogue, now via
// clang elementwise builtins on <2 x float> so the BACKEND selects
// v_pk_fma_f32 with correct modifiers (or scalarizes — correct either way).
// Staging = R3's proven register-prefetch + ds_write dbuf.

typedef __attribute__((ext_vector_type(8))) short short8;   // 8 bf16
typedef __attribute__((ext_vector_type(4))) float f32x4;
typedef __attribute__((ext_vector_type(2))) float f32x2;

#define KP 1024
#define DD 128

__device__ __forceinline__ unsigned int f2bf(float f) {
  unsigned int u = __float_as_uint(f);
  return (u + 0x7FFFu + ((u >> 16) & 1u)) >> 16;   // RNE fp32->bf16
}

// packed dual-fp32 via vector IR (backend emits v_pk_* on CDNA if available)
__device__ __forceinline__ f32x2 pk_fma(f32x2 a, f32x2 b, f32x2 c) {
  return __builtin_elementwise_fma(a, b, c);
}

// ---- prep: 32 blocks x 32 cols. Col norms -> inv, lw=log2(w)=-10*log2e*alpha,
// and bf16 normalized prototypes in staged layout: unit(16B) index =
// cg*1024 + w0*64 + c, cg=col>>6, c=col&63, w0=k/8.
__global__ __launch_bounds__(256) void prep_kernel(
    const float* __restrict__ mus, const float* __restrict__ alphas,
    uint4* __restrict__ musbf_sw, float* __restrict__ lw) {
  __shared__ float psum[8][32];
  __shared__ float Tt[32][129];
  __shared__ float inv_s[32];
  const int t = threadIdx.x;
  const int k0 = blockIdx.x * 32;
  const int kk = t & 31, gg = t >> 5;
  float s = 0.0f;
  for (int i = 0; i < 16; ++i) {
    float v = mus[(gg * 16 + i) * KP + k0 + kk];
    s = fmaf(v, v, s);
  }
  psum[gg][kk] = s;
  __syncthreads();
  if (t < 32) {
    float tot = 0.0f;
    for (int j = 0; j < 8; ++j) tot += psum[j][t];
    inv_s[t] = rsqrtf(tot);
    // log2(exp(-10*alpha)) = -10*log2(e)*alpha
    lw[k0 + t] = -14.4269504089f * alphas[k0 + t];
  }
  for (int i = 0; i < 16; ++i) {            // transpose 128x32 tile via LDS
    int e = i * 256 + t;
    Tt[e & 31][e >> 5] = mus[(e >> 5) * KP + k0 + (e & 31)];
  }
  __syncthreads();
  #pragma unroll
  for (int i = 0; i < 2; ++i) {             // 512 units, coalesced 16B writes
    int u = i * 256 + t;
    int w0 = u >> 5, c32 = u & 31;
    int col = k0 + c32;
    float inv = inv_s[c32];
    uint4 o;
    o.x = f2bf(Tt[c32][w0 * 8 + 0] * inv) | (f2bf(Tt[c32][w0 * 8 + 1] * inv) << 16);
    o.y = f2bf(Tt[c32][w0 * 8 + 2] * inv) | (f2bf(Tt[c32][w0 * 8 + 3] * inv) << 16);
    o.z = f2bf(Tt[c32][w0 * 8 + 4] * inv) | (f2bf(Tt[c32][w0 * 8 + 5] * inv) << 16);
    o.w = f2bf(Tt[c32][w0 * 8 + 6] * inv) | (f2bf(Tt[c32][w0 * 8 + 7] * inv) << 16);
    musbf_sw[((col >> 6) << 10) + (w0 << 6) + (col & 63)] = o;
  }
}

// ---- main: 1024 blocks x 256 thr (4 blocks/CU). Block b: rows b*64..+64,
// wave wv: rows +wv*16 (A regs). Loop cg=0..15 over 64-col groups: B staged
// into LDS dbuf with register prefetch (load(cg+1) -> compute(cg) ->
// ds_write(cg+1) -> barrier). Epilogue packed two-at-a-time via v2f32.
__global__ __launch_bounds__(256, 4) void main_kernel(
    const float* __restrict__ xs, const uint4* __restrict__ musbf_sw,
    const float* __restrict__ lw, float* __restrict__ out) {
  __shared__ __align__(16) unsigned short Bs[2][8192];   // 2 x 16 KB
  const int t = threadIdx.x;
  const int wv = t >> 6, ln = t & 63, q = ln >> 4, l15 = ln & 15;

  // A fragments: afr[kkk] = xs[row][kkk*32 + q*8 .. +8], row = block*64+wv*16+l15
  const int row = blockIdx.x * 64 + wv * 16 + l15;
  const float4* xs4 = (const float4*)xs;
  const int base4 = row * 32 + q * 2;
  short8 afr[4];
  #pragma unroll
  for (int kkk = 0; kkk < 4; ++kkk) {
    float4 f0 = xs4[base4 + kkk * 8];
    float4 f1 = xs4[base4 + kkk * 8 + 1];
    union { short8 s; uint4 u; } a;
    a.u.x = f2bf(f0.x) | (f2bf(f0.y) << 16);
    a.u.y = f2bf(f0.z) | (f2bf(f0.w) << 16);
    a.u.z = f2bf(f1.x) | (f2bf(f1.y) << 16);
    a.u.w = f2bf(f1.z) | (f2bf(f1.w) << 16);
    afr[kkk] = a.s;
  }

  // prefetch cg0 into buf0
  uint4 v[4];
  #pragma unroll
  for (int i = 0; i < 4; ++i) v[i] = musbf_sw[i * 256 + t];
  #pragma unroll
  for (int i = 0; i < 4; ++i) *(uint4*)&Bs[0][(i * 256 + t) * 8] = v[i];
  __syncthreads();

  // packed constants (register pairs, loop-invariant)
  const f32x2 C_mh = {-0.5f, -0.5f}, C_ph = {0.5f, 0.5f};
  const f32x2 C_z0 = {0.0f, 0.0f};
  const f32x2 C5 = {-3.6067376f, -3.6067376f};
  const f32x2 C4 = {-2.3449500f, -2.3449500f};
  const f32x2 C3 = {-3.2975886f, -3.2975886f};
  const f32x2 C2 = {-5.1295823f, -5.1295823f};
  const f32x2 C1 = {-9.6179669f, -9.6179669f};
  const f32x2 C0 = {-28.8539008f, -28.8539008f};

  f32x2 sums2[2] = {(f32x2){0.f, 0.f}, (f32x2){0.f, 0.f}};   // rows (0,1),(2,3)

  for (int cg = 0; cg < 16; ++cg) {
    if (cg < 15) {                        // issue next-B loads (overlap compute)
      #pragma unroll
      for (int i = 0; i < 4; ++i)
        v[i] = musbf_sw[(cg + 1) * 1024 + i * 256 + t];
    }
    float lwv[4];
    #pragma unroll
    for (int nt = 0; nt < 4; ++nt) lwv[nt] = lw[cg * 64 + nt * 16 + l15];

    f32x4 acc[4];
    #pragma unroll
    for (int nt = 0; nt < 4; ++nt) acc[nt] = (f32x4){0.f, 0.f, 0.f, 0.f};
    // B frag LDS short-offset: kkk*2048 + q*512 + nt*128 + l15*8
    const unsigned short* bp = &Bs[cg & 1][q * 512 + l15 * 8];
    #pragma unroll
    for (int kkk = 0; kkk < 4; ++kkk)
      #pragma unroll
      for (int nt = 0; nt < 4; ++nt) {
        short8 b = *(const short8*)(bp + kkk * 2048 + nt * 128);
        acc[nt] = __builtin_amdgcn_mfma_f32_16x16x32_bf16(afr[kkk], b, acc[nt], 0, 0, 0);
      }

    // packed epilogue: term = exp2(z*H(z) + lw), z=(1-x)/2
    #pragma unroll
    for (int nt = 0; nt < 4; ++nt) {
      f32x2 lwp = {lwv[nt], lwv[nt]};
      #pragma unroll
      for (int p = 0; p < 2; ++p) {
        f32x2 x = {acc[nt][2 * p], acc[nt][2 * p + 1]};
        f32x2 z = pk_fma(x, C_mh, C_ph);
        z = __builtin_elementwise_max(z, C_z0);
        f32x2 h = pk_fma(z, C5, C4);
        h = pk_fma(z, h, C3);
        h = pk_fma(z, h, C2);
        h = pk_fma(z, h, C1);
        h = pk_fma(z, h, C0);
        f32x2 arg = pk_fma(z, h, lwp);
        f32x2 e = {__builtin_amdgcn_exp2f(arg.x), __builtin_amdgcn_exp2f(arg.y)};
        sums2[p] = sums2[p] + e;
      }
    }

    if (cg < 15) {                        // commit prefetch to other buffer
      #pragma unroll
      for (int i = 0; i < 4; ++i)
        *(uint4*)&Bs[(cg + 1) & 1][(i * 256 + t) * 8] = v[i];
      __syncthreads();
    }
  }

  // one reduce over the 16 col-lanes; rows = q*4+r
  float s[4] = {sums2[0].x, sums2[0].y, sums2[1].x, sums2[1].y};
  #pragma unroll
  for (int s2 = 1; s2 < 16; s2 <<= 1)
    #pragma unroll
    for (int r = 0; r < 4; ++r) s[r] += __shfl_xor(s[r], s2, 64);
  if (l15 == 0) {
    #pragma unroll
    for (int r = 0; r < 4; ++r)
      out[blockIdx.x * 64 + wv * 16 + q * 4 + r] = 0.1f * log1pf(1.0f / s[r]);
  }
}

extern "C" void kernel_launch(void* const* d_in, const int* in_sizes, int n_in,
                              void* d_out, int out_size, void* d_ws, size_t ws_size,
                              hipStream_t stream) {
  const float* xs     = (const float*)d_in[0];   // [65536,128]
  const float* mus    = (const float*)d_in[1];   // [128,1024]
  const float* alphas = (const float*)d_in[2];   // [1024]
  float* out = (float*)d_out;

  uint4* musbf_sw = (uint4*)d_ws;                              // 256 KiB
  float* lw = (float*)((char*)d_ws + 16384 * sizeof(uint4));   // 4 KiB

  prep_kernel<<<KP / 32, 256, 0, stream>>>(mus, alphas, musbf_sw, lw);
  const int B = in_sizes[0] / DD;   // 65536
  main_kernel<<<B / 64, 256, 0, stream>>>(xs, musbf_sw, lw, out);
}